// Round 5
// baseline (3192.918 us; speedup 1.0000x reference)
//
#include <hip/hip_runtime.h>
#include <hip/hip_bf16.h>

#define DIMN 512
#define NHEAD 8
#define HD 64
#define NPROT 256
#define NHW 4096
#define NB 4
#define NTOT 44000

__device__ __forceinline__ int batch_of(int r) {
    return (r < 12000) ? 0 : (r < 22000) ? 1 : (r < 36000) ? 2 : 3;
}

// ---------------- 64x64-tile fp32 GEMM (small M) ----------------
template<bool TRANS_A, bool ACCUM, bool HAS_BIAS>
__device__ __forceinline__ void gemm_body(
    const float* __restrict__ A, const float* __restrict__ B,
    const float* __restrict__ bias, float* __restrict__ C,
    int M, int N, int K, int lda, int m0, int n0)
{
    __shared__ float As[16][64];
    __shared__ float Bs[16][64];
    const int t  = threadIdx.x;
    const int tx = t & 15, ty = t >> 4;
    float acc[4][4] = {};

    for (int k0 = 0; k0 < K; k0 += 16) {
        if (TRANS_A) {
            const int kk = t >> 4, mf = t & 15;
            const int m = m0 + mf * 4;
            float4 a = make_float4(0.f, 0.f, 0.f, 0.f);
            if (m < M) a = *(const float4*)&A[(size_t)(k0 + kk) * lda + m];
            *(float4*)&As[kk][mf * 4] = a;
        } else {
            const int mm = t >> 2, kf = t & 3;
            const int m = m0 + mm;
            float4 a = make_float4(0.f, 0.f, 0.f, 0.f);
            if (m < M) a = *(const float4*)&A[(size_t)m * lda + k0 + kf * 4];
            As[kf * 4 + 0][mm] = a.x;
            As[kf * 4 + 1][mm] = a.y;
            As[kf * 4 + 2][mm] = a.z;
            As[kf * 4 + 3][mm] = a.w;
        }
        {
            const int kk = t >> 4, nf = t & 15;
            *(float4*)&Bs[kk][nf * 4] = *(const float4*)&B[(size_t)(k0 + kk) * N + n0 + nf * 4];
        }
        __syncthreads();
#pragma unroll
        for (int kk = 0; kk < 16; ++kk) {
            const float4 a = *(const float4*)&As[kk][ty * 4];
            const float4 b = *(const float4*)&Bs[kk][tx * 4];
            const float av[4] = {a.x, a.y, a.z, a.w};
            const float bv[4] = {b.x, b.y, b.z, b.w};
#pragma unroll
            for (int i = 0; i < 4; ++i)
#pragma unroll
                for (int j = 0; j < 4; ++j) acc[i][j] += av[i] * bv[j];
        }
        __syncthreads();
    }

    float4 bb = make_float4(0.f, 0.f, 0.f, 0.f);
    if (HAS_BIAS) bb = *(const float4*)&bias[n0 + tx * 4];
#pragma unroll
    for (int i = 0; i < 4; ++i) {
        const int m = m0 + ty * 4 + i;
        if (m < M) {
            float* cp = &C[(size_t)m * N + n0 + tx * 4];
            float4 r;
            if (ACCUM) {
                const float4 o = *(const float4*)cp;
                r = make_float4(o.x + acc[i][0], o.y + acc[i][1], o.z + acc[i][2], o.w + acc[i][3]);
            } else {
                r = make_float4(acc[i][0] + bb.x, acc[i][1] + bb.y, acc[i][2] + bb.z, acc[i][3] + bb.w);
            }
            *(float4*)cp = r;
        }
    }
}

template<bool TRANS_A, bool ACCUM, bool HAS_BIAS>
__global__ __launch_bounds__(256)
void gemm_f32(const float* __restrict__ A, const float* __restrict__ B,
              const float* __restrict__ bias, float* __restrict__ C,
              int M, int N, int K, int lda)
{
    gemm_body<TRANS_A, ACCUM, HAS_BIAS>(A, B, bias, C, M, N, K, lda,
                                        blockIdx.x * 64, blockIdx.y * 64);
}

// ---------------- 128x128-tile fp32 GEMM, 8x8 microtile ----------------
// Staging + compute phases arranged so all compute LDS reads are <=2-way bank aliased.
template<bool TRANS_A>
__device__ __forceinline__ void gemm128_ktile(
    const float* __restrict__ A, const float* __restrict__ B,
    float As[16][128], float Bs[16][128],
    int M, int K, int N, int lda, int m0, int n0, int k0, int t,
    float acc[8][8])
{
    if (TRANS_A) {
#pragma unroll
        for (int p = 0; p < 2; ++p) {
            const int idx = t + p * 256;
            const int kk = idx >> 5, mf = idx & 31;
            const int m = m0 + mf * 4;
            float4 a = make_float4(0.f, 0.f, 0.f, 0.f);
            if (m < M) a = *(const float4*)&A[(size_t)(k0 + kk) * lda + m];
            *(float4*)&As[kk][mf * 4] = a;
        }
    } else {
#pragma unroll
        for (int p = 0; p < 2; ++p) {
            const int idx = t + p * 256;
            const int row = idx >> 2, kf = idx & 3;
            const int m = m0 + row;
            float4 a = make_float4(0.f, 0.f, 0.f, 0.f);
            if (m < M) a = *(const float4*)&A[(size_t)m * lda + k0 + kf * 4];
            As[kf * 4 + 0][row] = a.x;
            As[kf * 4 + 1][row] = a.y;
            As[kf * 4 + 2][row] = a.z;
            As[kf * 4 + 3][row] = a.w;
        }
    }
#pragma unroll
    for (int p = 0; p < 2; ++p) {
        const int idx = t + p * 256;
        const int kk = idx >> 5, nf = idx & 31;
        *(float4*)&Bs[kk][nf * 4] = *(const float4*)&B[(size_t)(k0 + kk) * N + n0 + nf * 4];
    }
    __syncthreads();
    const int tx = t & 15, ty = t >> 4;
#pragma unroll
    for (int kk = 0; kk < 16; ++kk) {
        const float4 a0 = *(const float4*)&As[kk][ty * 4];
        const float4 a1 = *(const float4*)&As[kk][64 + ty * 4];
        const float4 b0 = *(const float4*)&Bs[kk][tx * 4];
        const float4 b1 = *(const float4*)&Bs[kk][64 + tx * 4];
        const float av[8] = {a0.x, a0.y, a0.z, a0.w, a1.x, a1.y, a1.z, a1.w};
        const float bv[8] = {b0.x, b0.y, b0.z, b0.w, b1.x, b1.y, b1.z, b1.w};
#pragma unroll
        for (int i = 0; i < 8; ++i)
#pragma unroll
            for (int j = 0; j < 8; ++j) acc[i][j] += av[i] * bv[j];
    }
    __syncthreads();
}

__device__ __forceinline__ void gemm128_store(
    float* __restrict__ C, const float* __restrict__ bias,
    int M, int N, int m0, int n0, int t, float acc[8][8])
{
    const int tx = t & 15, ty = t >> 4;
    float4 bb0 = make_float4(0.f, 0.f, 0.f, 0.f);
    float4 bb1 = make_float4(0.f, 0.f, 0.f, 0.f);
    if (bias) {
        bb0 = *(const float4*)&bias[n0 + tx * 4];
        bb1 = *(const float4*)&bias[n0 + 64 + tx * 4];
    }
#pragma unroll
    for (int i = 0; i < 8; ++i) {
        const int m = m0 + ((i < 4) ? (ty * 4 + i) : (64 + ty * 4 + i - 4));
        if (m < M) {
            float* cp = &C[(size_t)m * N + n0 + tx * 4];
            *(float4*)cp = make_float4(acc[i][0] + bb0.x, acc[i][1] + bb0.y,
                                       acc[i][2] + bb0.z, acc[i][3] + bb0.w);
            float* cp2 = cp + 64;
            *(float4*)cp2 = make_float4(acc[i][4] + bb1.x, acc[i][5] + bb1.y,
                                        acc[i][6] + bb1.z, acc[i][7] + bb1.w);
        }
    }
}

template<bool TRANS_A, bool HAS_BIAS>
__global__ __launch_bounds__(256)
void gemm128_f32(const float* __restrict__ A, const float* __restrict__ B,
                 const float* __restrict__ bias, float* __restrict__ C,
                 int M, int N, int K, int lda)
{
    __shared__ float As[16][128];
    __shared__ float Bs[16][128];
    const int t = threadIdx.x;
    const int m0 = blockIdx.x * 128, n0 = blockIdx.y * 128;
    float acc[8][8] = {};
    for (int k0 = 0; k0 < K; k0 += 16)
        gemm128_ktile<TRANS_A>(A, B, As, Bs, M, K, N, lda, m0, n0, k0, t, acc);
    gemm128_store(C, HAS_BIAS ? bias : nullptr, M, N, m0, n0, t, acc);
}

// k1/v1: per (b, proj): C[4096,512] = range_mu[b]^T @ W + bias. grid.z = b*2+proj.
__global__ __launch_bounds__(256)
void k1v1_gemm128(const float* __restrict__ range_mu,
                  const float* __restrict__ Wk, const float* __restrict__ bk,
                  const float* __restrict__ Wv, const float* __restrict__ bv,
                  float* __restrict__ k1, float* __restrict__ v1)
{
    __shared__ float As[16][128];
    __shared__ float Bs[16][128];
    const int z = blockIdx.z;
    const int b = z >> 1, p = z & 1;
    const float* A  = range_mu + (size_t)b * DIMN * NHW;
    const float* W  = p ? Wv : Wk;
    const float* bi = p ? bv : bk;
    float* C = (p ? v1 : k1) + (size_t)b * NHW * DIMN;
    const int t = threadIdx.x;
    const int m0 = blockIdx.x * 128, n0 = blockIdx.y * 128;
    float acc[8][8] = {};
    for (int k0 = 0; k0 < DIMN; k0 += 16)
        gemm128_ktile<true>(A, W, As, Bs, NHW, DIMN, DIMN, NHW, m0, n0, k0, t, acc);
    gemm128_store(C, bi, NHW, DIMN, m0, n0, t, acc);
}

// tail: X = fusion_z@Wpt_top + voxel@Wpt_bot + O2@Wc + bc   (K = 3x512 accumulated in regs)
__global__ __launch_bounds__(256)
void tail_fused(const float* __restrict__ fz,  const float* __restrict__ Wt,
                const float* __restrict__ vox, const float* __restrict__ Wb,
                const float* __restrict__ O2,  const float* __restrict__ Wc,
                const float* __restrict__ bc,  float* __restrict__ X)
{
    __shared__ float As[16][128];
    __shared__ float Bs[16][128];
    const int t = threadIdx.x;
    const int m0 = blockIdx.x * 128, n0 = blockIdx.y * 128;
    float acc[8][8] = {};
    const float* Aarr[3] = {fz, vox, O2};
    const float* Barr[3] = {Wt, Wb, Wc};
#pragma unroll
    for (int s = 0; s < 3; ++s) {
        const float* A = Aarr[s];
        const float* B = Barr[s];
        for (int k0 = 0; k0 < DIMN; k0 += 16)
            gemm128_ktile<false>(A, B, As, Bs, NTOT, DIMN, DIMN, DIMN, m0, n0, k0, t, acc);
    }
    gemm128_store(X, bc, NTOT, DIMN, m0, n0, t, acc);
}

// ---------------- MHA stage 1: 256 protos x 4096 keys, flash-style ----------------
__global__ __launch_bounds__(256)
void mha1_kernel(const float* __restrict__ q1,   // [256, 512]
                 const float* __restrict__ k1,   // [B, 4096, 512]
                 const float* __restrict__ v1,
                 float* __restrict__ outh)       // [B, 256, 512] concat heads
{
    const int h = blockIdx.y, b = blockIdx.z;
    const int q0 = blockIdx.x * 32;
    const int t = threadIdx.x;
    const int qi = t >> 3;   // 0..31
    const int tp = t & 7;    // 0..7
    __shared__ float qs[32][68];
    __shared__ float ks[64][68];
    __shared__ float vs[64][68];
    __shared__ float ps[32][68];

    for (int i = t; i < 32 * 16; i += 256) {
        const int r = i >> 4, cf = i & 15;
        *(float4*)&qs[r][cf * 4] = *(const float4*)&q1[(size_t)(q0 + r) * DIMN + h * 64 + cf * 4];
    }
    float m = -1e30f, l = 0.f;
    float o[8] = {0, 0, 0, 0, 0, 0, 0, 0};
    const float* kb = k1 + (size_t)b * NHW * DIMN + h * 64;
    const float* vb = v1 + (size_t)b * NHW * DIMN + h * 64;

    for (int kt = 0; kt < NHW; kt += 64) {
        __syncthreads();
        for (int i = t; i < 64 * 16; i += 256) {
            const int r = i >> 4, cf = i & 15;
            *(float4*)&ks[r][cf * 4] = *(const float4*)&kb[(size_t)(kt + r) * DIMN + cf * 4];
            *(float4*)&vs[r][cf * 4] = *(const float4*)&vb[(size_t)(kt + r) * DIMN + cf * 4];
        }
        __syncthreads();
        float s[8];
        float mt = -1e30f;
#pragma unroll
        for (int j = 0; j < 8; ++j) {
            const int kj = tp + 8 * j;
            float acc = 0.f;
#pragma unroll
            for (int e = 0; e < 64; e += 4) {
                const float4 qv = *(const float4*)&qs[qi][e];
                const float4 kv = *(const float4*)&ks[kj][e];
                acc += qv.x * kv.x + qv.y * kv.y + qv.z * kv.z + qv.w * kv.w;
            }
            s[j] = acc * 0.125f;
            mt = fmaxf(mt, s[j]);
        }
        mt = fmaxf(mt, __shfl_xor(mt, 1));
        mt = fmaxf(mt, __shfl_xor(mt, 2));
        mt = fmaxf(mt, __shfl_xor(mt, 4));
        const float mn = fmaxf(m, mt);
        const float alpha = __expf(m - mn);
        float lt = 0.f;
#pragma unroll
        for (int j = 0; j < 8; ++j) {
            s[j] = __expf(s[j] - mn);
            lt += s[j];
            ps[qi][tp + 8 * j] = s[j];
        }
        lt += __shfl_xor(lt, 1);
        lt += __shfl_xor(lt, 2);
        lt += __shfl_xor(lt, 4);
        l = l * alpha + lt;
        m = mn;
#pragma unroll
        for (int j = 0; j < 8; ++j) o[j] *= alpha;
        __syncthreads();
#pragma unroll 4
        for (int kj = 0; kj < 64; ++kj) {
            const float p = ps[qi][kj];
            const float4 va = *(const float4*)&vs[kj][tp * 8];
            const float4 vc = *(const float4*)&vs[kj][tp * 8 + 4];
            o[0] += p * va.x; o[1] += p * va.y; o[2] += p * va.z; o[3] += p * va.w;
            o[4] += p * vc.x; o[5] += p * vc.y; o[6] += p * vc.z; o[7] += p * vc.w;
        }
    }
    const float inv = 1.f / l;
    float* op = outh + ((size_t)b * NPROT + q0 + qi) * DIMN + h * 64 + tp * 8;
    *(float4*)&op[0] = make_float4(o[0] * inv, o[1] * inv, o[2] * inv, o[3] * inv);
    *(float4*)&op[4] = make_float4(o[4] * inv, o[5] * inv, o[6] * inv, o[7] * inv);
}

// ---------------- MHA stage 2: 44000 ragged rows x 256 keys (exact softmax) ----------------
__global__ __launch_bounds__(256)
void mha2_kernel(const float* __restrict__ Q2,   // [44000, 512]
                 const float* __restrict__ k2,   // [B, 256, 512]
                 const float* __restrict__ v2,
                 float* __restrict__ O2)         // [44000, 512] pre-Wo2 head outputs
{
    const int r0 = blockIdx.x * 16;
    const int b = batch_of(r0);
    const int t = threadIdx.x;
    const int qi = t >> 4;   // 0..15
    const int tp = t & 15;   // 0..15
    __shared__ float qs[16][68];
    __shared__ float ks[64][68];
    __shared__ float ss[16][260];
    const float* kbase = k2 + (size_t)b * NPROT * DIMN;
    const float* vbase = v2 + (size_t)b * NPROT * DIMN;

    for (int h = 0; h < NHEAD; ++h) {
        __syncthreads();
        {
            const int r = t >> 4, cf = t & 15;
            *(float4*)&qs[r][cf * 4] = *(const float4*)&Q2[(size_t)(r0 + r) * DIMN + h * 64 + cf * 4];
        }
        for (int kt = 0; kt < NPROT; kt += 64) {
            __syncthreads();
            for (int i = t; i < 64 * 16; i += 256) {
                const int r = i >> 4, cf = i & 15;
                *(float4*)&ks[r][cf * 4] = *(const float4*)&kbase[(size_t)(kt + r) * DIMN + h * 64 + cf * 4];
            }
            __syncthreads();
#pragma unroll
            for (int j = 0; j < 4; ++j) {
                const int kj = tp + 16 * j;
                float acc = 0.f;
#pragma unroll
                for (int e = 0; e < 64; e += 4) {
                    const float4 qv = *(const float4*)&qs[qi][e];
                    const float4 kv = *(const float4*)&ks[kj][e];
                    acc += qv.x * kv.x + qv.y * kv.y + qv.z * kv.z + qv.w * kv.w;
                }
                ss[qi][kt + kj] = acc * 0.125f;
            }
        }
        __syncthreads();
        float sv[16];
        float mx = -1e30f;
#pragma unroll
        for (int i = 0; i < 16; ++i) { sv[i] = ss[qi][tp + 16 * i]; mx = fmaxf(mx, sv[i]); }
        mx = fmaxf(mx, __shfl_xor(mx, 1));
        mx = fmaxf(mx, __shfl_xor(mx, 2));
        mx = fmaxf(mx, __shfl_xor(mx, 4));
        mx = fmaxf(mx, __shfl_xor(mx, 8));
        float ls = 0.f;
#pragma unroll
        for (int i = 0; i < 16; ++i) { sv[i] = __expf(sv[i] - mx); ls += sv[i]; }
        ls += __shfl_xor(ls, 1);
        ls += __shfl_xor(ls, 2);
        ls += __shfl_xor(ls, 4);
        ls += __shfl_xor(ls, 8);
        const float inv = 1.f / ls;
#pragma unroll
        for (int i = 0; i < 16; ++i) ss[qi][tp + 16 * i] = sv[i] * inv;
        __syncthreads();
        float o[4] = {0, 0, 0, 0};
        for (int kt = 0; kt < NPROT; kt += 64) {
            __syncthreads();
            for (int i = t; i < 64 * 16; i += 256) {
                const int r = i >> 4, cf = i & 15;
                *(float4*)&ks[r][cf * 4] = *(const float4*)&vbase[(size_t)(kt + r) * DIMN + h * 64 + cf * 4];
            }
            __syncthreads();
#pragma unroll 8
            for (int kj = 0; kj < 64; ++kj) {
                const float p = ss[qi][kt + kj];
                const float4 v = *(const float4*)&ks[kj][tp * 4];
                o[0] += p * v.x; o[1] += p * v.y; o[2] += p * v.z; o[3] += p * v.w;
            }
        }
        float* op = O2 + (size_t)(r0 + qi) * DIMN + h * 64 + tp * 4;
        *(float4*)op = make_float4(o[0], o[1], o[2], o[3]);
    }
}

// ---------------- tail helpers ----------------
__global__ void zero_kernel(float* __restrict__ p, int n)
{
    const int i = blockIdx.x * 256 + threadIdx.x;
    if (i < n) p[i] = 0.f;
}

__global__ void bias_comb_kernel(const float* __restrict__ bo2, const float* __restrict__ Wpt,
                                 const float* __restrict__ bpt, float* __restrict__ out)
{
    const int d = threadIdx.x;   // 512 threads
    float acc = bpt[d];
    for (int c = 0; c < DIMN; ++c) acc += bo2[c] * Wpt[(size_t)(DIMN + c) * DIMN + d];
    out[d] = acc;
}

__global__ __launch_bounds__(512)
void bn_stats_kernel(const float* __restrict__ X, float* __restrict__ sums, float* __restrict__ sumsq)
{
    const int c = threadIdx.x;          // 0..511
    const int rows_per = (NTOT + gridDim.x - 1) / gridDim.x;
    const int r0 = blockIdx.x * rows_per;
    int r1 = r0 + rows_per;
    if (r1 > NTOT) r1 = NTOT;
    float s = 0.f, s2 = 0.f;
    for (int r = r0; r < r1; ++r) {
        const float x = X[(size_t)r * DIMN + c];
        s += x;
        s2 += x * x;
    }
    atomicAdd(&sums[c], s);
    atomicAdd(&sumsq[c], s2);
}

__global__ void bn_finalize_kernel(const float* __restrict__ sums, const float* __restrict__ sumsq,
                                   const float* __restrict__ gamma, const float* __restrict__ beta,
                                   float* __restrict__ scale, float* __restrict__ shift)
{
    const int c = threadIdx.x;          // 512 threads
    const float mean = sums[c] * (1.f / NTOT);
    const float var = sumsq[c] * (1.f / NTOT) - mean * mean;
    const float inv = 1.f / sqrtf(var + 1e-5f);   // IEEE sqrt, not rsqrt approx
    const float sc = gamma[c] * inv;
    scale[c] = sc;
    shift[c] = beta[c] - mean * sc;
}

__global__ __launch_bounds__(256)
void bn_apply_kernel(float* __restrict__ X, const float* __restrict__ scale, const float* __restrict__ shift)
{
    const int n4 = NTOT * DIMN / 4;
    const int stride = gridDim.x * 256;
    for (int idx = blockIdx.x * 256 + threadIdx.x; idx < n4; idx += stride) {
        const int c4 = (idx & 127) * 4;
        float4 x = ((float4*)X)[idx];
        const float4 sc = *(const float4*)&scale[c4];
        const float4 sh = *(const float4*)&shift[c4];
        x.x = fmaxf(0.f, x.x * sc.x + sh.x);
        x.y = fmaxf(0.f, x.y * sc.y + sh.y);
        x.z = fmaxf(0.f, x.z * sc.z + sh.z);
        x.w = fmaxf(0.f, x.w * sc.w + sh.w);
        ((float4*)X)[idx] = x;
    }
}

extern "C" void kernel_launch(void* const* d_in, const int* in_sizes, int n_in,
                              void* d_out, int out_size, void* d_ws, size_t ws_size,
                              hipStream_t stream)
{
    const float* voxel      = (const float*)d_in[0];
    const float* range_mu   = (const float*)d_in[1];
    const float* fusion_z   = (const float*)d_in[2];
    const float* prototypes = (const float*)d_in[8];
    const float* Wq1 = (const float*)d_in[9];  const float* bq1 = (const float*)d_in[10];
    const float* Wk1 = (const float*)d_in[11]; const float* bk1 = (const float*)d_in[12];
    const float* Wv1 = (const float*)d_in[13]; const float* bv1 = (const float*)d_in[14];
    const float* Wo1 = (const float*)d_in[15]; const float* bo1 = (const float*)d_in[16];
    const float* Wq2 = (const float*)d_in[17]; const float* bq2 = (const float*)d_in[18];
    const float* Wk2 = (const float*)d_in[19]; const float* bk2 = (const float*)d_in[20];
    const float* Wv2 = (const float*)d_in[21]; const float* bv2 = (const float*)d_in[22];
    const float* Wo2 = (const float*)d_in[23]; const float* bo2 = (const float*)d_in[24];
    const float* Wpt = (const float*)d_in[25]; const float* bpt = (const float*)d_in[26];
    const float* gamma = (const float*)d_in[27]; const float* beta = (const float*)d_in[28];

    float* f = (float*)d_ws;
    // layout (floats). O2 overlays k1/v1 (dead by the time MHA2 runs).
    float* k1buf = f;                                   // 4*4096*512 = 8,388,608
    float* v1buf = f + (size_t)NB * NHW * DIMN;         // +8,388,608
    float* O2    = f;                                   // 22,528,000 (44000*512)
    float* q1buf = f + (size_t)NTOT * DIMN;             // 131,072
    float* mh1   = q1buf + NPROT * DIMN;                // 524,288
    float* attz  = mh1 + (size_t)NB * NPROT * DIMN;     // 524,288
    float* k2buf = attz + (size_t)NB * NPROT * DIMN;    // 524,288
    float* v2buf = k2buf + (size_t)NB * NPROT * DIMN;   // 524,288
    float* Wc    = v2buf + (size_t)NB * NPROT * DIMN;   // 262,144
    float* bc    = Wc + DIMN * DIMN;                    // 512
    float* sums  = bc + DIMN;                           // 512
    float* ssq   = sums + DIMN;                         // 512
    float* scl   = ssq + DIMN;                          // 512
    float* shf   = scl + DIMN;                          // 512

    float* Q2 = (float*)d_out;   // d_out doubles as Q2 scratch, overwritten by tail GEMM
    const dim3 blk(256);

    // stage 1 projections (128-tile, trans-A)
    k1v1_gemm128<<<dim3(32, 4, 8), blk, 0, stream>>>(range_mu, Wk1, bk1, Wv1, bv1, k1buf, v1buf);
    gemm_f32<false, false, true><<<dim3(4, 8), blk, 0, stream>>>(prototypes, Wq1, bq1, q1buf, NPROT, DIMN, DIMN, DIMN);
    // stage 1 attention + output projection
    mha1_kernel<<<dim3(8, 8, 4), blk, 0, stream>>>(q1buf, k1buf, v1buf, mh1);
    gemm_f32<false, false, true><<<dim3(16, 8), blk, 0, stream>>>(mh1, Wo1, bo1, attz, NB * NPROT, DIMN, DIMN, DIMN);
    // stage 2 k/v projections
    gemm_f32<false, false, true><<<dim3(16, 8), blk, 0, stream>>>(attz, Wk2, bk2, k2buf, NB * NPROT, DIMN, DIMN, DIMN);
    gemm_f32<false, false, true><<<dim3(16, 8), blk, 0, stream>>>(attz, Wv2, bv2, v2buf, NB * NPROT, DIMN, DIMN, DIMN);
    // Q2 = voxel @ Wq2 + bq2 (into d_out as scratch)
    gemm128_f32<false, true><<<dim3(344, 4), blk, 0, stream>>>(voxel, Wq2, bq2, Q2, NTOT, DIMN, DIMN, DIMN);
    // folded tail weights: Wc = Wo2 @ Wpt[512:], bc = bo2 @ Wpt[512:] + bpt
    gemm_f32<false, false, false><<<dim3(8, 8), blk, 0, stream>>>(Wo2, Wpt + DIMN * DIMN, nullptr, Wc, DIMN, DIMN, DIMN, DIMN);
    bias_comb_kernel<<<1, 512, 0, stream>>>(bo2, Wpt, bpt, bc);
    // stage 2 attention (pre-Wo2 heads) into O2 (overlays dead k1/v1)
    mha2_kernel<<<dim3(2750), blk, 0, stream>>>(Q2, k2buf, v2buf, O2);
    // fused tail: X = fusion_z@Wpt_top + voxel@Wpt_bot + O2@Wc + bc  (into d_out)
    tail_fused<<<dim3(344, 4), blk, 0, stream>>>(fusion_z, Wpt, voxel, Wpt + (size_t)DIMN * DIMN, O2, Wc, bc, (float*)d_out);
    // BatchNorm (batch stats) + ReLU, in place on d_out
    zero_kernel<<<dim3(4), blk, 0, stream>>>(sums, 2 * DIMN);   // zeroes sums+ssq (contiguous)
    bn_stats_kernel<<<dim3(256), dim3(512), 0, stream>>>((const float*)d_out, sums, ssq);
    bn_finalize_kernel<<<1, 512, 0, stream>>>(sums, ssq, gamma, beta, scl, shf);
    bn_apply_kernel<<<dim3(2048), blk, 0, stream>>>((float*)d_out, scl, shf);
}

// Round 7
// 2174.977 us; speedup vs baseline: 1.4680x; 1.4680x over previous
//
#include <hip/hip_runtime.h>
#include <hip/hip_bf16.h>

#define DIMN 512
#define NHEAD 8
#define HD 64
#define NPROT 256
#define NHW 4096
#define NB 4
#define NTOT 44000

typedef _Float16 half8 __attribute__((ext_vector_type(8)));
typedef float f32x4 __attribute__((ext_vector_type(4)));

__device__ __forceinline__ int batch_of(int r) {
    return (r < 12000) ? 0 : (r < 22000) ? 1 : (r < 36000) ? 2 : 3;
}

// ---------------- 64x64-tile fp32 GEMM (small M only) ----------------
template<bool TRANS_A, bool ACCUM, bool HAS_BIAS>
__device__ __forceinline__ void gemm_body(
    const float* __restrict__ A, const float* __restrict__ B,
    const float* __restrict__ bias, float* __restrict__ C,
    int M, int N, int K, int lda, int m0, int n0)
{
    __shared__ float As[16][64];
    __shared__ float Bs[16][64];
    const int t  = threadIdx.x;
    const int tx = t & 15, ty = t >> 4;
    float acc[4][4] = {};

    for (int k0 = 0; k0 < K; k0 += 16) {
        if (TRANS_A) {
            const int kk = t >> 4, mf = t & 15;
            const int m = m0 + mf * 4;
            float4 a = make_float4(0.f, 0.f, 0.f, 0.f);
            if (m < M) a = *(const float4*)&A[(size_t)(k0 + kk) * lda + m];
            *(float4*)&As[kk][mf * 4] = a;
        } else {
            const int mm = t >> 2, kf = t & 3;
            const int m = m0 + mm;
            float4 a = make_float4(0.f, 0.f, 0.f, 0.f);
            if (m < M) a = *(const float4*)&A[(size_t)m * lda + k0 + kf * 4];
            As[kf * 4 + 0][mm] = a.x;
            As[kf * 4 + 1][mm] = a.y;
            As[kf * 4 + 2][mm] = a.z;
            As[kf * 4 + 3][mm] = a.w;
        }
        {
            const int kk = t >> 4, nf = t & 15;
            *(float4*)&Bs[kk][nf * 4] = *(const float4*)&B[(size_t)(k0 + kk) * N + n0 + nf * 4];
        }
        __syncthreads();
#pragma unroll
        for (int kk = 0; kk < 16; ++kk) {
            const float4 a = *(const float4*)&As[kk][ty * 4];
            const float4 b = *(const float4*)&Bs[kk][tx * 4];
            const float av[4] = {a.x, a.y, a.z, a.w};
            const float bv[4] = {b.x, b.y, b.z, b.w};
#pragma unroll
            for (int i = 0; i < 4; ++i)
#pragma unroll
                for (int j = 0; j < 4; ++j) acc[i][j] += av[i] * bv[j];
        }
        __syncthreads();
    }

    float4 bb = make_float4(0.f, 0.f, 0.f, 0.f);
    if (HAS_BIAS) bb = *(const float4*)&bias[n0 + tx * 4];
#pragma unroll
    for (int i = 0; i < 4; ++i) {
        const int m = m0 + ty * 4 + i;
        if (m < M) {
            float* cp = &C[(size_t)m * N + n0 + tx * 4];
            float4 r;
            if (ACCUM) {
                const float4 o = *(const float4*)cp;
                r = make_float4(o.x + acc[i][0], o.y + acc[i][1], o.z + acc[i][2], o.w + acc[i][3]);
            } else {
                r = make_float4(acc[i][0] + bb.x, acc[i][1] + bb.y, acc[i][2] + bb.z, acc[i][3] + bb.w);
            }
            *(float4*)cp = r;
        }
    }
}

template<bool TRANS_A, bool ACCUM, bool HAS_BIAS>
__global__ __launch_bounds__(256)
void gemm_f32(const float* __restrict__ A, const float* __restrict__ B,
              const float* __restrict__ bias, float* __restrict__ C,
              int M, int N, int K, int lda)
{
    gemm_body<TRANS_A, ACCUM, HAS_BIAS>(A, B, bias, C, M, N, K, lda,
                                        blockIdx.x * 64, blockIdx.y * 64);
}

// ---------------- f16 MFMA GEMM: 128x128 tile, BK=32, 4 waves ----------------
// LDS layout: [row][k] f16, 32 k/row = 4 chunks of 16B; chunk XOR-swizzled by (row&3).
// Read-side: 64 lanes map uniformly to 8 bank-starts (structural minimum, conflict-free).
__device__ __forceinline__ int lds_off(int row, int k) {
    return row * 32 + ((((k >> 3) ^ row) & 3) << 3) + (k & 7);
}

// stage A-tile (row-major [M][lda]) -> As[128][32] f16, converting fp32->f16
__device__ __forceinline__ void stage_rowmajor(const float* __restrict__ A, _Float16* As,
                                               int M, int lda, int m0, int k0, int t)
{
    const int row = t >> 1;
#pragma unroll
    for (int p = 0; p < 2; ++p) {
        const int koff = (t & 1) + 2 * p;              // 0..3
        const int gr = m0 + row;
        float4 x0 = make_float4(0.f, 0.f, 0.f, 0.f), x1 = x0;
        if (gr < M) {
            const float* src = &A[(size_t)gr * lda + k0 + koff * 8];
            x0 = *(const float4*)src;
            x1 = *(const float4*)(src + 4);
        }
        half8 h;
        h[0] = (_Float16)x0.x; h[1] = (_Float16)x0.y; h[2] = (_Float16)x0.z; h[3] = (_Float16)x0.w;
        h[4] = (_Float16)x1.x; h[5] = (_Float16)x1.y; h[6] = (_Float16)x1.z; h[7] = (_Float16)x1.w;
        *(half8*)&As[lds_off(row, koff * 8)] = h;
    }
}

// stage transposed tile (source [K][ldc], want Ls[col][k]) with fp32->f16 conversion.
// reads are 4B/lane but fully coalesced (lane = consecutive cols).
__device__ __forceinline__ void stage_transpose(const float* __restrict__ A, _Float16* Ls,
                                                int ldc, int c0, int k0, int t)
{
    const int c = t & 127;
    const int kb = t >> 7;                              // 0 or 1
#pragma unroll
    for (int p = 0; p < 2; ++p) {
        const int koff = kb + 2 * p;                    // 0..3
        const float* src = &A[(size_t)(k0 + koff * 8) * ldc + c0 + c];
        half8 h;
#pragma unroll
        for (int i = 0; i < 8; ++i) h[i] = (_Float16)src[(size_t)i * ldc];
        *(half8*)&Ls[lds_off(c, koff * 8)] = h;
    }
}

__device__ __forceinline__ void mfma_ktile(const _Float16* As, const _Float16* Bs,
                                           int t, f32x4 acc[4][4])
{
    const int l = t & 63, w = t >> 6;
    const int wr = (w >> 1) * 64, wc = (w & 1) * 64;
    const int lr = l & 15, lk = (l >> 4) * 8;
    half8 av[4], bv[4];
#pragma unroll
    for (int m = 0; m < 4; ++m) av[m] = *(const half8*)&As[lds_off(wr + m * 16 + lr, lk)];
#pragma unroll
    for (int n = 0; n < 4; ++n) bv[n] = *(const half8*)&Bs[lds_off(wc + n * 16 + lr, lk)];
#pragma unroll
    for (int m = 0; m < 4; ++m)
#pragma unroll
        for (int n = 0; n < 4; ++n)
            acc[m][n] = __builtin_amdgcn_mfma_f32_16x16x32_f16(av[m], bv[n], acc[m][n], 0, 0, 0);
}

// C/D mapping (verified m89/m91): col = lane&15, row = (lane>>4)*4 + reg
__device__ __forceinline__ void mfma_store(float* __restrict__ C, const float* __restrict__ bias,
                                           int M, int ldc, int m0, int n0, int t, f32x4 acc[4][4])
{
    const int l = t & 63, w = t >> 6;
    const int wr = (w >> 1) * 64, wc = (w & 1) * 64;
    const int col0 = n0 + wc + (l & 15);
    const int rbase = m0 + wr + ((l >> 4) << 2);
#pragma unroll
    for (int m = 0; m < 4; ++m)
#pragma unroll
        for (int j = 0; j < 4; ++j) {
            const int r = rbase + m * 16 + j;
            if (r < M) {
#pragma unroll
                for (int n = 0; n < 4; ++n) {
                    const int c = col0 + n * 16;
                    C[(size_t)r * ldc + c] = acc[m][n][j] + (bias ? bias[c] : 0.f);
                }
            }
        }
}

// NSRC row-major sources sharing one output tile: C = sum_s A_s @ B_s (+bias)
template<int NSRC>
__global__ __launch_bounds__(256)
void gemm_mfma_nn(const float* __restrict__ A0, const float* __restrict__ B0,
                  const float* __restrict__ A1, const float* __restrict__ B1,
                  const float* __restrict__ A2, const float* __restrict__ B2,
                  const float* __restrict__ bias, float* __restrict__ C,
                  int M, int N, int K)
{
    __shared__ _Float16 As[128 * 32];
    __shared__ _Float16 Bs[128 * 32];
    const int t = threadIdx.x;
    const int m0 = blockIdx.x * 128, n0 = blockIdx.y * 128;
    f32x4 acc[4][4] = {};
    const float* Aarr[3] = {A0, A1, A2};
    const float* Barr[3] = {B0, B1, B2};
#pragma unroll
    for (int s = 0; s < NSRC; ++s) {
        const float* A = Aarr[s];
        const float* B = Barr[s];
        for (int k0 = 0; k0 < K; k0 += 32) {
            __syncthreads();
            stage_rowmajor(A, As, M, K, m0, k0, t);
            stage_transpose(B, Bs, N, n0, k0, t);      // B is [K][N]
            __syncthreads();
            mfma_ktile(As, Bs, t, acc);
        }
    }
    mfma_store(C, bias, M, N, m0, n0, t, acc);
}

// k1/v1: per (b, proj): C[4096,512] = range_mu[b]^T @ W + bias. grid.z = b*2+proj.
__global__ __launch_bounds__(256)
void k1v1_mfma(const float* __restrict__ range_mu,
               const float* __restrict__ Wk, const float* __restrict__ bk,
               const float* __restrict__ Wv, const float* __restrict__ bv,
               float* __restrict__ k1, float* __restrict__ v1)
{
    __shared__ _Float16 As[128 * 32];
    __shared__ _Float16 Bs[128 * 32];
    const int z = blockIdx.z;
    const int b = z >> 1, p = z & 1;
    const float* A  = range_mu + (size_t)b * DIMN * NHW;   // [K=512][M=4096]
    const float* W  = p ? Wv : Wk;                          // [K=512][N=512]
    const float* bi = p ? bv : bk;
    float* C = (p ? v1 : k1) + (size_t)b * NHW * DIMN;
    const int t = threadIdx.x;
    const int m0 = blockIdx.x * 128, n0 = blockIdx.y * 128;
    f32x4 acc[4][4] = {};
    for (int k0 = 0; k0 < DIMN; k0 += 32) {
        __syncthreads();
        stage_transpose(A, As, NHW, m0, k0, t);   // A^T tile
        stage_transpose(W, Bs, DIMN, n0, k0, t);
        __syncthreads();
        mfma_ktile(As, Bs, t, acc);
    }
    mfma_store(C, bi, NHW, DIMN, m0, n0, t, acc);
}

// ---------------- MHA stage 1: 256 protos x 4096 keys, flash-style ----------------
__global__ __launch_bounds__(256)
void mha1_kernel(const float* __restrict__ q1,   // [256, 512]
                 const float* __restrict__ k1,   // [B, 4096, 512]
                 const float* __restrict__ v1,
                 float* __restrict__ outh)       // [B, 256, 512] concat heads
{
    const int h = blockIdx.y, b = blockIdx.z;
    const int q0 = blockIdx.x * 32;
    const int t = threadIdx.x;
    const int qi = t >> 3;   // 0..31
    const int tp = t & 7;    // 0..7
    __shared__ float qs[32][68];
    __shared__ float ks[64][68];
    __shared__ float vs[64][68];
    __shared__ float ps[32][68];

    for (int i = t; i < 32 * 16; i += 256) {
        const int r = i >> 4, cf = i & 15;
        *(float4*)&qs[r][cf * 4] = *(const float4*)&q1[(size_t)(q0 + r) * DIMN + h * 64 + cf * 4];
    }
    float m = -1e30f, l = 0.f;
    float o[8] = {0, 0, 0, 0, 0, 0, 0, 0};
    const float* kb = k1 + (size_t)b * NHW * DIMN + h * 64;
    const float* vb = v1 + (size_t)b * NHW * DIMN + h * 64;

    for (int kt = 0; kt < NHW; kt += 64) {
        __syncthreads();
        for (int i = t; i < 64 * 16; i += 256) {
            const int r = i >> 4, cf = i & 15;
            *(float4*)&ks[r][cf * 4] = *(const float4*)&kb[(size_t)(kt + r) * DIMN + cf * 4];
            *(float4*)&vs[r][cf * 4] = *(const float4*)&vb[(size_t)(kt + r) * DIMN + cf * 4];
        }
        __syncthreads();
        float s[8];
        float mt = -1e30f;
#pragma unroll
        for (int j = 0; j < 8; ++j) {
            const int kj = tp + 8 * j;
            float acc = 0.f;
#pragma unroll
            for (int e = 0; e < 64; e += 4) {
                const float4 qv = *(const float4*)&qs[qi][e];
                const float4 kv = *(const float4*)&ks[kj][e];
                acc += qv.x * kv.x + qv.y * kv.y + qv.z * kv.z + qv.w * kv.w;
            }
            s[j] = acc * 0.125f;
            mt = fmaxf(mt, s[j]);
        }
        mt = fmaxf(mt, __shfl_xor(mt, 1));
        mt = fmaxf(mt, __shfl_xor(mt, 2));
        mt = fmaxf(mt, __shfl_xor(mt, 4));
        const float mn = fmaxf(m, mt);
        const float alpha = __expf(m - mn);
        float lt = 0.f;
#pragma unroll
        for (int j = 0; j < 8; ++j) {
            s[j] = __expf(s[j] - mn);
            lt += s[j];
            ps[qi][tp + 8 * j] = s[j];
        }
        lt += __shfl_xor(lt, 1);
        lt += __shfl_xor(lt, 2);
        lt += __shfl_xor(lt, 4);
        l = l * alpha + lt;
        m = mn;
#pragma unroll
        for (int j = 0; j < 8; ++j) o[j] *= alpha;
        __syncthreads();
#pragma unroll 4
        for (int kj = 0; kj < 64; ++kj) {
            const float p = ps[qi][kj];
            const float4 va = *(const float4*)&vs[kj][tp * 8];
            const float4 vc = *(const float4*)&vs[kj][tp * 8 + 4];
            o[0] += p * va.x; o[1] += p * va.y; o[2] += p * va.z; o[3] += p * va.w;
            o[4] += p * vc.x; o[5] += p * vc.y; o[6] += p * vc.z; o[7] += p * vc.w;
        }
    }
    const float inv = 1.f / l;
    float* op = outh + ((size_t)b * NPROT + q0 + qi) * DIMN + h * 64 + tp * 8;
    *(float4*)&op[0] = make_float4(o[0] * inv, o[1] * inv, o[2] * inv, o[3] * inv);
    *(float4*)&op[4] = make_float4(o[4] * inv, o[5] * inv, o[6] * inv, o[7] * inv);
}

// ---------------- MHA stage 2: 44000 ragged rows x 256 keys (exact softmax) ----------------
__global__ __launch_bounds__(256)
void mha2_kernel(const float* __restrict__ Q2,   // [44000, 512]
                 const float* __restrict__ k2,   // [B, 256, 512]
                 const float* __restrict__ v2,
                 float* __restrict__ O2)         // [44000, 512] pre-Wo2 head outputs
{
    const int r0 = blockIdx.x * 16;
    const int b = batch_of(r0);
    const int t = threadIdx.x;
    const int qi = t >> 4;   // 0..15
    const int tp = t & 15;   // 0..15
    __shared__ float qs[16][68];
    __shared__ float ks[64][68];
    __shared__ float ss[16][260];
    const float* kbase = k2 + (size_t)b * NPROT * DIMN;
    const float* vbase = v2 + (size_t)b * NPROT * DIMN;

    for (int h = 0; h < NHEAD; ++h) {
        __syncthreads();
        {
            const int r = t >> 4, cf = t & 15;
            *(float4*)&qs[r][cf * 4] = *(const float4*)&Q2[(size_t)(r0 + r) * DIMN + h * 64 + cf * 4];
        }
        for (int kt = 0; kt < NPROT; kt += 64) {
            __syncthreads();
            for (int i = t; i < 64 * 16; i += 256) {
                const int r = i >> 4, cf = i & 15;
                *(float4*)&ks[r][cf * 4] = *(const float4*)&kbase[(size_t)(kt + r) * DIMN + h * 64 + cf * 4];
            }
            __syncthreads();
#pragma unroll
            for (int j = 0; j < 4; ++j) {
                const int kj = tp + 16 * j;
                float acc = 0.f;
#pragma unroll
                for (int e = 0; e < 64; e += 4) {
                    const float4 qv = *(const float4*)&qs[qi][e];
                    const float4 kv = *(const float4*)&ks[kj][e];
                    acc += qv.x * kv.x + qv.y * kv.y + qv.z * kv.z + qv.w * kv.w;
                }
                ss[qi][kt + kj] = acc * 0.125f;
            }
        }
        __syncthreads();
        float sv[16];
        float mx = -1e30f;
#pragma unroll
        for (int i = 0; i < 16; ++i) { sv[i] = ss[qi][tp + 16 * i]; mx = fmaxf(mx, sv[i]); }
        mx = fmaxf(mx, __shfl_xor(mx, 1));
        mx = fmaxf(mx, __shfl_xor(mx, 2));
        mx = fmaxf(mx, __shfl_xor(mx, 4));
        mx = fmaxf(mx, __shfl_xor(mx, 8));
        float ls = 0.f;
#pragma unroll
        for (int i = 0; i < 16; ++i) { sv[i] = __expf(sv[i] - mx); ls += sv[i]; }
        ls += __shfl_xor(ls, 1);
        ls += __shfl_xor(ls, 2);
        ls += __shfl_xor(ls, 4);
        ls += __shfl_xor(ls, 8);
        const float inv = 1.f / ls;
#pragma unroll
        for (int i = 0; i < 16; ++i) ss[qi][tp + 16 * i] = sv[i] * inv;
        __syncthreads();
        float o[4] = {0, 0, 0, 0};
        for (int kt = 0; kt < NPROT; kt += 64) {
            __syncthreads();
            for (int i = t; i < 64 * 16; i += 256) {
                const int r = i >> 4, cf = i & 15;
                *(float4*)&ks[r][cf * 4] = *(const float4*)&vbase[(size_t)(kt + r) * DIMN + h * 64 + cf * 4];
            }
            __syncthreads();
#pragma unroll 8
            for (int kj = 0; kj < 64; ++kj) {
                const float p = ss[qi][kt + kj];
                const float4 v = *(const float4*)&ks[kj][tp * 4];
                o[0] += p * v.x; o[1] += p * v.y; o[2] += p * v.z; o[3] += p * v.w;
            }
        }
        float* op = O2 + (size_t)(r0 + qi) * DIMN + h * 64 + tp * 4;
        *(float4*)op = make_float4(o[0], o[1], o[2], o[3]);
    }
}

// ---------------- tail helpers ----------------
__global__ void zero_kernel(float* __restrict__ p, int n)
{
    const int i = blockIdx.x * 256 + threadIdx.x;
    if (i < n) p[i] = 0.f;
}

__global__ void bias_comb_kernel(const float* __restrict__ bo2, const float* __restrict__ Wpt,
                                 const float* __restrict__ bpt, float* __restrict__ out)
{
    const int d = threadIdx.x;   // 512 threads
    float acc = bpt[d];
    for (int c = 0; c < DIMN; ++c) acc += bo2[c] * Wpt[(size_t)(DIMN + c) * DIMN + d];
    out[d] = acc;
}

__global__ __launch_bounds__(512)
void bn_stats_kernel(const float* __restrict__ X, float* __restrict__ sums, float* __restrict__ sumsq)
{
    const int c = threadIdx.x;          // 0..511
    const int rows_per = (NTOT + gridDim.x - 1) / gridDim.x;
    const int r0 = blockIdx.x * rows_per;
    int r1 = r0 + rows_per;
    if (r1 > NTOT) r1 = NTOT;
    float s = 0.f, s2 = 0.f;
    for (int r = r0; r < r1; ++r) {
        const float x = X[(size_t)r * DIMN + c];
        s += x;
        s2 += x * x;
    }
    atomicAdd(&sums[c], s);
    atomicAdd(&sumsq[c], s2);
}

__global__ void bn_finalize_kernel(const float* __restrict__ sums, const float* __restrict__ sumsq,
                                   const float* __restrict__ gamma, const float* __restrict__ beta,
                                   float* __restrict__ scale, float* __restrict__ shift)
{
    const int c = threadIdx.x;          // 512 threads
    const float mean = sums[c] * (1.f / NTOT);
    const float var = sumsq[c] * (1.f / NTOT) - mean * mean;
    const float inv = 1.f / sqrtf(var + 1e-5f);   // IEEE sqrt, not rsqrt approx
    const float sc = gamma[c] * inv;
    scale[c] = sc;
    shift[c] = beta[c] - mean * sc;
}

__global__ __launch_bounds__(256)
void bn_apply_kernel(float* __restrict__ X, const float* __restrict__ scale, const float* __restrict__ shift)
{
    const int n4 = NTOT * DIMN / 4;
    const int stride = gridDim.x * 256;
    for (int idx = blockIdx.x * 256 + threadIdx.x; idx < n4; idx += stride) {
        const int c4 = (idx & 127) * 4;
        float4 x = ((float4*)X)[idx];
        const float4 sc = *(const float4*)&scale[c4];
        const float4 sh = *(const float4*)&shift[c4];
        x.x = fmaxf(0.f, x.x * sc.x + sh.x);
        x.y = fmaxf(0.f, x.y * sc.y + sh.y);
        x.z = fmaxf(0.f, x.z * sc.z + sh.z);
        x.w = fmaxf(0.f, x.w * sc.w + sh.w);
        ((float4*)X)[idx] = x;
    }
}

extern "C" void kernel_launch(void* const* d_in, const int* in_sizes, int n_in,
                              void* d_out, int out_size, void* d_ws, size_t ws_size,
                              hipStream_t stream)
{
    const float* voxel      = (const float*)d_in[0];
    const float* range_mu   = (const float*)d_in[1];
    const float* fusion_z   = (const float*)d_in[2];
    const float* prototypes = (const float*)d_in[8];
    const float* Wq1 = (const float*)d_in[9];  const float* bq1 = (const float*)d_in[10];
    const float* Wk1 = (const float*)d_in[11]; const float* bk1 = (const float*)d_in[12];
    const float* Wv1 = (const float*)d_in[13]; const float* bv1 = (const float*)d_in[14];
    const float* Wo1 = (const float*)d_in[15]; const float* bo1 = (const float*)d_in[16];
    const float* Wq2 = (const float*)d_in[17]; const float* bq2 = (const float*)d_in[18];
    const float* Wk2 = (const float*)d_in[19]; const float* bk2 = (const float*)d_in[20];
    const float* Wv2 = (const float*)d_in[21]; const float* bv2 = (const float*)d_in[22];
    const float* Wo2 = (const float*)d_in[23]; const float* bo2 = (const float*)d_in[24];
    const float* Wpt = (const float*)d_in[25]; const float* bpt = (const float*)d_in[26];
    const float* gamma = (const float*)d_in[27]; const float* beta = (const float*)d_in[28];

    float* f = (float*)d_ws;
    // layout (floats). O2 overlays k1/v1 (dead by the time MHA2 runs).
    float* k1buf = f;                                   // 4*4096*512 = 8,388,608
    float* v1buf = f + (size_t)NB * NHW * DIMN;         // +8,388,608
    float* O2    = f;                                   // 22,528,000 (44000*512)
    float* q1buf = f + (size_t)NTOT * DIMN;             // 131,072
    float* mh1   = q1buf + NPROT * DIMN;                // 524,288
    float* attz  = mh1 + (size_t)NB * NPROT * DIMN;     // 524,288
    float* k2buf = attz + (size_t)NB * NPROT * DIMN;    // 524,288
    float* v2buf = k2buf + (size_t)NB * NPROT * DIMN;   // 524,288
    float* Wc    = v2buf + (size_t)NB * NPROT * DIMN;   // 262,144
    float* bc    = Wc + DIMN * DIMN;                    // 512
    float* sums  = bc + DIMN;                           // 512
    float* ssq   = sums + DIMN;                         // 512
    float* scl   = ssq + DIMN;                          // 512
    float* shf   = scl + DIMN;                          // 512

    float* Q2 = (float*)d_out;   // d_out doubles as Q2 scratch, overwritten by tail GEMM
    const dim3 blk(256);

    // stage 1 projections: k1/v1 via f16 MFMA (trans-A staging)
    k1v1_mfma<<<dim3(32, 4, 8), blk, 0, stream>>>(range_mu, Wk1, bk1, Wv1, bv1, k1buf, v1buf);
    gemm_f32<false, false, true><<<dim3(4, 8), blk, 0, stream>>>(prototypes, Wq1, bq1, q1buf, NPROT, DIMN, DIMN, DIMN);
    // stage 1 attention + output projection
    mha1_kernel<<<dim3(8, 8, 4), blk, 0, stream>>>(q1buf, k1buf, v1buf, mh1);
    gemm_f32<false, false, true><<<dim3(16, 8), blk, 0, stream>>>(mh1, Wo1, bo1, attz, NB * NPROT, DIMN, DIMN, DIMN);
    // stage 2 k/v projections
    gemm_f32<false, false, true><<<dim3(16, 8), blk, 0, stream>>>(attz, Wk2, bk2, k2buf, NB * NPROT, DIMN, DIMN, DIMN);
    gemm_f32<false, false, true><<<dim3(16, 8), blk, 0, stream>>>(attz, Wv2, bv2, v2buf, NB * NPROT, DIMN, DIMN, DIMN);
    // Q2 = voxel @ Wq2 + bq2 (f16 MFMA, into d_out as scratch)
    gemm_mfma_nn<1><<<dim3(344, 4), blk, 0, stream>>>(voxel, Wq2, nullptr, nullptr, nullptr, nullptr,
                                                      bq2, Q2, NTOT, DIMN, DIMN);
    // folded tail weights: Wc = Wo2 @ Wpt[512:], bc = bo2 @ Wpt[512:] + bpt
    gemm_f32<false, false, false><<<dim3(8, 8), blk, 0, stream>>>(Wo2, Wpt + DIMN * DIMN, nullptr, Wc, DIMN, DIMN, DIMN, DIMN);
    bias_comb_kernel<<<1, 512, 0, stream>>>(bo2, Wpt, bpt, bc);
    // stage 2 attention (pre-Wo2 heads) into O2 (overlays dead k1/v1)
    mha2_kernel<<<dim3(2750), blk, 0, stream>>>(Q2, k2buf, v2buf, O2);
    // fused tail (f16 MFMA): X = fusion_z@Wpt_top + voxel@Wpt_bot + O2@Wc + bc
    gemm_mfma_nn<3><<<dim3(344, 4), blk, 0, stream>>>(fusion_z, Wpt, voxel, Wpt + (size_t)DIMN * DIMN,
                                                      O2, Wc, bc, (float*)d_out, NTOT, DIMN, DIMN);
    // BatchNorm (batch stats) + ReLU, in place on d_out
    zero_kernel<<<dim3(4), blk, 0, stream>>>(sums, 2 * DIMN);   // zeroes sums+ssq (contiguous)
    bn_stats_kernel<<<dim3(256), dim3(512), 0, stream>>>((const float*)d_out, sums, ssq);
    bn_finalize_kernel<<<1, 512, 0, stream>>>(sums, ssq, gamma, beta, scl, shf);
    bn_apply_kernel<<<dim3(2048), blk, 0, stream>>>((float*)d_out, scl, shf);
}